// Round 1
// baseline (15.959 us; speedup 1.0000x reference)
//
#include <hip/hip_runtime.h>

#define CIN   3
#define COUT  4
#define NWGT  9
#define BATCH 32
#define HDIM  128
#define WDIM  128
#define NH    125   // (128 - 3 + 1 - 1) / 1
#define NWO   125

// RY(theta) on qubit Q of an 8-dim real state held in registers.
// Pairs are (i, i + (1<<Q)) for every i with bit Q clear.
template<int Q>
__device__ __forceinline__ void apply_ry_cs(float (&p)[8], float c, float s) {
    constexpr int lo = 1 << Q;
    #pragma unroll
    for (int i = 0; i < 8; ++i) {
        if ((i & lo) == 0) {
            float a = p[i];
            float b = p[i + lo];
            p[i]      = c * a - s * b;
            p[i + lo] = s * a + c * b;
        }
    }
}

template<int Q>
__device__ __forceinline__ void apply_ry(float (&p)[8], float ang) {
    float s, c;
    __sincosf(0.5f * ang, &s, &c);
    apply_ry_cs<Q>(p, c, s);
}

__global__ __launch_bounds__(256) void quanv_kernel(
        const float* __restrict__ X,
        const float* __restrict__ Wg,
        float* __restrict__ out) {
    // --- per-block: 3 threads compute the W-dependent base states into LDS ---
    __shared__ float sPsi[CIN][8];
    const int t = threadIdx.x;
    if (t < CIN) {
        float p[8];
        #pragma unroll
        for (int m = 0; m < 8; ++m) p[m] = 0.35355339059327373f; // 1/sqrt(8)
        #pragma unroll
        for (int wi = 0; wi < NWGT; ++wi) {
            float ang = Wg[t * NWGT + wi];
            if      (wi % 3 == 0) apply_ry<0>(p, ang);
            else if (wi % 3 == 1) apply_ry<1>(p, ang);
            else                  apply_ry<2>(p, ang);
        }
        // CX(0,1): new[j] = old[j ^ ((j&1)<<1)]
        float q1[8];
        #pragma unroll
        for (int j = 0; j < 8; ++j) q1[j] = p[j ^ ((j & 1) << 1)];
        // CX(1,2): new[j] = old[j ^ (((j>>1)&1)<<2)]
        #pragma unroll
        for (int j = 0; j < 8; ++j) sPsi[t][j] = q1[j ^ (((j >> 1) & 1) << 2)];
    }
    __syncthreads();

    const int tid = blockIdx.x * blockDim.x + threadIdx.x;
    if (tid >= BATCH * HDIM * WDIM) return;
    const int w = tid % WDIM;
    const int h = (tid / WDIM) % HDIM;
    const int b = tid / (WDIM * HDIM);

    float acc[COUT] = {0.f, 0.f, 0.f, 0.f};

    if (h < NH && w < NWO) {
        #pragma unroll
        for (int c = 0; c < CIN; ++c) {
            float p[8];
            #pragma unroll
            for (int m = 0; m < 8; ++m) p[m] = sPsi[c][m];

            const float* xp = X + (((size_t)b * CIN + c) * HDIM + h) * WDIM + w;
            #pragma unroll
            for (int dh = 0; dh < 3; ++dh) {
                const float x0 = xp[dh * WDIM + 0];
                const float x1 = xp[dh * WDIM + 1];
                const float x2 = xp[dh * WDIM + 2];
                apply_ry<0>(p, x0);   // gate p=3*dh+0, qubit 0
                apply_ry<1>(p, x1);   // qubit 1
                apply_ry<2>(p, x2);   // qubit 2
            }
            // Data-side CX(0,1),CX(1,2) + (state % 4) bucketing folded into a
            // static class map: class(m) = b0 + 2*(b1^b0) -> [0,3,2,1,0,3,2,1]
            acc[0] += p[0] * p[0] + p[4] * p[4];
            acc[3] += p[1] * p[1] + p[5] * p[5];
            acc[2] += p[2] * p[2] + p[6] * p[6];
            acc[1] += p[3] * p[3] + p[7] * p[7];
        }
    }
    // padding region (h>=125 or w>=125) writes zeros — required every launch
    float* o = out + ((size_t)b * COUT * HDIM * WDIM) + (size_t)h * WDIM + w;
    #pragma unroll
    for (int c = 0; c < COUT; ++c) o[(size_t)c * HDIM * WDIM] = acc[c];
}

extern "C" void kernel_launch(void* const* d_in, const int* in_sizes, int n_in,
                              void* d_out, int out_size, void* d_ws, size_t ws_size,
                              hipStream_t stream) {
    const float* X  = (const float*)d_in[0];   // (32, 3, 128, 128) f32
    const float* Wg = (const float*)d_in[1];   // (3, 9) f32
    float* out = (float*)d_out;                // (32, 4, 128, 128) f32

    const int total  = BATCH * HDIM * WDIM;    // 524288
    const int block  = 256;
    const int grid   = (total + block - 1) / block;  // 2048
    quanv_kernel<<<grid, block, 0, stream>>>(X, Wg, out);
}

// Round 2
// 11.769 us; speedup vs baseline: 1.3560x; 1.3560x over previous
//
#include <hip/hip_runtime.h>

#define CIN   3
#define COUT  4
#define NWGT  9
#define BATCH 32
#define HDIM  128
#define WDIM  128
#define NH    125   // (128 - 3 + 1 - 1) / 1
#define NWO   125

// RY(theta) on qubit Q of an 8-dim real state held in registers.
template<int Q>
__device__ __forceinline__ void apply_ry_cs(float (&p)[8], float c, float s) {
    constexpr int lo = 1 << Q;
    #pragma unroll
    for (int i = 0; i < 8; ++i) {
        if ((i & lo) == 0) {
            float a = p[i];
            float b = p[i + lo];
            p[i]      = c * a - s * b;
            p[i + lo] = s * a + c * b;
        }
    }
}

template<int Q>
__device__ __forceinline__ void apply_ry(float (&p)[8], float ang) {
    float s, c;
    __sincosf(0.5f * ang, &s, &c);
    apply_ry_cs<Q>(p, c, s);
}

__global__ __launch_bounds__(256) void quanv_kernel(
        const float* __restrict__ X,
        const float* __restrict__ Wg,
        float* __restrict__ out) {
    // --- per-block: 3 threads compute the W-dependent base states into LDS ---
    // W circuit: 9 RY gates (qubit wi%3) + CX(0,1) + CX(1,2). RYs on distinct
    // qubits commute; same-qubit RYs compose additively -> 3 gates.
    __shared__ float sPsi[CIN][8];
    const int t = threadIdx.x;
    if (t < CIN) {
        const float* wr = Wg + t * NWGT;
        const float a0 = wr[0] + wr[3] + wr[6];
        const float a1 = wr[1] + wr[4] + wr[7];
        const float a2 = wr[2] + wr[5] + wr[8];
        float p[8];
        #pragma unroll
        for (int m = 0; m < 8; ++m) p[m] = 0.35355339059327373f; // 1/sqrt(8)
        apply_ry<0>(p, a0);
        apply_ry<1>(p, a1);
        apply_ry<2>(p, a2);
        // CX(0,1): new[j] = old[j ^ ((j&1)<<1)]
        float q1[8];
        #pragma unroll
        for (int j = 0; j < 8; ++j) q1[j] = p[j ^ ((j & 1) << 1)];
        // CX(1,2): new[j] = old[j ^ (((j>>1)&1)<<2)]
        #pragma unroll
        for (int j = 0; j < 8; ++j) sPsi[t][j] = q1[j ^ (((j >> 1) & 1) << 2)];
    }
    __syncthreads();

    const int tid = blockIdx.x * blockDim.x + threadIdx.x;
    if (tid >= BATCH * HDIM * WDIM) return;
    const int w = tid % WDIM;
    const int h = (tid / WDIM) % HDIM;
    const int b = tid / (WDIM * HDIM);

    float acc[COUT] = {0.f, 0.f, 0.f, 0.f};

    if (h < NH && w < NWO) {
        #pragma unroll
        for (int c = 0; c < CIN; ++c) {
            const float* xp = X + (((size_t)b * CIN + c) * HDIM + h) * WDIM + w;
            // Data circuit collapse: gate p (qubit p%3=dw, angle X[h+dh][w+dw])
            // -> RY_q( sum_dh X[h+dh][w+q] ) : vertical 3-tap column sums.
            const float s0 = xp[0] + xp[WDIM]     + xp[2 * WDIM];
            const float s1 = xp[1] + xp[WDIM + 1] + xp[2 * WDIM + 1];
            const float s2 = xp[2] + xp[WDIM + 2] + xp[2 * WDIM + 2];

            float p[8];
            #pragma unroll
            for (int m = 0; m < 8; ++m) p[m] = sPsi[c][m];
            apply_ry<0>(p, s0);
            apply_ry<1>(p, s1);
            apply_ry<2>(p, s2);

            // CX(0,1),CX(1,2) + (state % 4) folded into static class map:
            // class(m) = b0 + 2*(b1^b0) -> [0,3,2,1,0,3,2,1]
            acc[0] += p[0] * p[0] + p[4] * p[4];
            acc[3] += p[1] * p[1] + p[5] * p[5];
            acc[2] += p[2] * p[2] + p[6] * p[6];
            acc[1] += p[3] * p[3] + p[7] * p[7];
        }
    }
    // padding region (h>=125 or w>=125) writes zeros — required every launch
    float* o = out + ((size_t)b * COUT * HDIM * WDIM) + (size_t)h * WDIM + w;
    #pragma unroll
    for (int c = 0; c < COUT; ++c) o[(size_t)c * HDIM * WDIM] = acc[c];
}

extern "C" void kernel_launch(void* const* d_in, const int* in_sizes, int n_in,
                              void* d_out, int out_size, void* d_ws, size_t ws_size,
                              hipStream_t stream) {
    const float* X  = (const float*)d_in[0];   // (32, 3, 128, 128) f32
    const float* Wg = (const float*)d_in[1];   // (3, 9) f32
    float* out = (float*)d_out;                // (32, 4, 128, 128) f32

    const int total  = BATCH * HDIM * WDIM;    // 524288
    const int block  = 256;
    const int grid   = (total + block - 1) / block;  // 2048
    quanv_kernel<<<grid, block, 0, stream>>>(X, Wg, out);
}

// Round 3
// 10.344 us; speedup vs baseline: 1.5429x; 1.1378x over previous
//
#include <hip/hip_runtime.h>

#define CIN   3
#define NWGT  9
#define BATCH 32
#define HDIM  128
#define WDIM  128
#define NH    125
#define NWO   125

// RY(theta) on qubit Q of 8-dim real state (used only for the W-side base state).
template<int Q>
__device__ __forceinline__ void apply_ry(float (&p)[8], float ang) {
    float s, c;
    __sincosf(0.5f * ang, &s, &c);
    constexpr int lo = 1 << Q;
    #pragma unroll
    for (int i = 0; i < 8; ++i) {
        if ((i & lo) == 0) {
            float a = p[i], b = p[i + lo];
            p[i]      = c * a - s * b;
            p[i + lo] = s * a + c * b;
        }
    }
}

__global__ __launch_bounds__(256) void quanv_kernel(
        const float* __restrict__ X,
        const float* __restrict__ Wg,
        float* __restrict__ out) {
    // ---- per-block: 3 threads build 12 per-channel constants into LDS ----
    // Base state u = CX(1,2) CX(0,1) RY2 RY1 RY0 |+++>, with same-qubit W
    // angles summed. Data circuit: classes pair {m, m+4} (bit 2), so the
    // qubit-2 data rotation preserves every class sum -> DEAD. Remaining two
    // rotations expand (double-angle) to class sums linear in
    // (cos th0, sin th0) x (cos th1, sin th1) with constants from u.
    __shared__ float sC[CIN][12];
    const int t = threadIdx.x;
    if (t < CIN) {
        const float* wr = Wg + t * NWGT;
        float p[8];
        #pragma unroll
        for (int m = 0; m < 8; ++m) p[m] = 0.35355339059327373f; // 1/sqrt(8)
        apply_ry<0>(p, wr[0] + wr[3] + wr[6]);
        apply_ry<1>(p, wr[1] + wr[4] + wr[7]);
        apply_ry<2>(p, wr[2] + wr[5] + wr[8]);
        float q1[8], u[8];
        #pragma unroll
        for (int j = 0; j < 8; ++j) q1[j] = p[j ^ ((j & 1) << 1)];        // CX(0,1)
        #pragma unroll
        for (int j = 0; j < 8; ++j) u[j] = q1[j ^ (((j >> 1) & 1) << 2)]; // CX(1,2)

        const float P04 = u[0]*u[0] + u[4]*u[4], P15 = u[1]*u[1] + u[5]*u[5];
        const float P26 = u[2]*u[2] + u[6]*u[6], P37 = u[3]*u[3] + u[7]*u[7];
        const float K1 = 0.5f*(P04 + P15), K2 = 0.5f*(P04 - P15);
        const float K3 = -(u[0]*u[1] + u[4]*u[5]);
        const float L1 = 0.5f*(P26 + P37), L2 = 0.5f*(P26 - P37);
        const float L3 = -(u[2]*u[3] + u[6]*u[7]);
        const float C02 = u[0]*u[2] + u[4]*u[6], C13 = u[1]*u[3] + u[5]*u[7];
        const float M1 = 0.5f*(C02 + C13), M2 = 0.5f*(C02 - C13);
        const float M3 = -0.5f*(u[0]*u[3] + u[1]*u[2] + u[4]*u[7] + u[5]*u[6]);
        sC[t][0] = 0.5f*(K1 + L1); sC[t][1] = 0.5f*(K2 + L2); sC[t][2] = 0.5f*(K3 + L3);
        sC[t][3] = 0.5f*(K1 - L1); sC[t][4] = 0.5f*(K2 - L2); sC[t][5] = 0.5f*(K3 - L3);
        sC[t][6] = M1;             sC[t][7] = M2;             sC[t][8] = M3;
        sC[t][9]  = K1 + L1;       // 2*E1
        sC[t][10] = K1 - L1;       // 2*F1
        sC[t][11] = 2.0f * M1;     // 2*M1
    }
    __syncthreads();

    // ---- 4 pixels per thread along w; float4 row loads; 5 sincos / 4 px ----
    const int tid = blockIdx.x * blockDim.x + threadIdx.x;
    const int w0  = (tid & 31) << 2;          // 0,4,...,124
    const int row = tid >> 5;
    const int h   = row & (HDIM - 1);
    const int b   = row >> 7;

    float acc[4][4] = {{0.f}};
    if (h < NH) {
        const bool wfull = (w0 < 124);        // col w0+4 exists
        #pragma unroll
        for (int c = 0; c < CIN; ++c) {
            const float* base = X + (((size_t)b * CIN + c) << 14) + (h << 7) + w0;
            const float4 r0 = *(const float4*)(base);
            const float4 r1 = *(const float4*)(base + WDIM);
            const float4 r2 = *(const float4*)(base + 2 * WDIM);
            const float e0 = wfull ? base[4]            : 0.f;
            const float e1 = wfull ? base[WDIM + 4]     : 0.f;
            const float e2 = wfull ? base[2 * WDIM + 4] : 0.f;
            float cs[5];
            cs[0] = r0.x + r1.x + r2.x;
            cs[1] = r0.y + r1.y + r2.y;
            cs[2] = r0.z + r1.z + r2.z;
            cs[3] = r0.w + r1.w + r2.w;
            cs[4] = e0 + e1 + e2;
            float cc[5], sn[5];
            #pragma unroll
            for (int j = 0; j < 5; ++j) __sincosf(cs[j], &sn[j], &cc[j]);

            const float E1 = sC[c][0], E2 = sC[c][1], E3 = sC[c][2];
            const float F1 = sC[c][3], F2 = sC[c][4], F3 = sC[c][5];
            const float M1 = sC[c][6], M2 = sC[c][7], M3 = sC[c][8];
            const float E1x2 = sC[c][9], F1x2 = sC[c][10], M1x2 = sC[c][11];
            #pragma unroll
            for (int j = 0; j < 4; ++j) {
                const float cj = cc[j], sj = sn[j];
                const float c1 = cc[j + 1], s1 = sn[j + 1];
                const float e  = fmaf(E3, sj, fmaf(E2, cj, E1));
                const float f  = fmaf(F3, sj, fmaf(F2, cj, F1));
                const float g  = fmaf(M3, sj, fmaf(M2, cj, M1));
                const float ep = E1x2 - e, fp = F1x2 - f, gp = M1x2 - g;
                const float cls0 = fmaf(-g,  s1, fmaf(f,  c1, e));
                const float cls2 = fmaf(2.f, e,  -cls0);
                const float cls3 = fmaf(-gp, s1, fmaf(fp, c1, ep));
                const float cls1 = fmaf(2.f, ep, -cls3);
                acc[0][j] += cls0; acc[1][j] += cls1;
                acc[2][j] += cls2; acc[3][j] += cls3;
            }
        }
        // zero the padding pixels (only w0==124 has j>=1 invalid)
        #pragma unroll
        for (int j = 0; j < 4; ++j)
            if (w0 + j >= NWO)
                acc[0][j] = acc[1][j] = acc[2][j] = acc[3][j] = 0.f;
    }
    float* ob = out + (((size_t)b * 4) << 14) + (h << 7) + w0;
    #pragma unroll
    for (int k = 0; k < 4; ++k)
        *(float4*)(ob + ((size_t)k << 14)) =
            make_float4(acc[k][0], acc[k][1], acc[k][2], acc[k][3]);
}

extern "C" void kernel_launch(void* const* d_in, const int* in_sizes, int n_in,
                              void* d_out, int out_size, void* d_ws, size_t ws_size,
                              hipStream_t stream) {
    const float* X  = (const float*)d_in[0];   // (32, 3, 128, 128) f32
    const float* Wg = (const float*)d_in[1];   // (3, 9) f32
    float* out = (float*)d_out;                // (32, 4, 128, 128) f32

    const int total = BATCH * HDIM * (WDIM / 4);  // 131072 threads, 4 px each
    quanv_kernel<<<total / 256, 256, 0, stream>>>(X, Wg, out);
}

// Round 4
// 10.196 us; speedup vs baseline: 1.5653x; 1.0145x over previous
//
#include <hip/hip_runtime.h>

#define CIN   3
#define NWGT  9
#define BATCH 32
#define HDIM  128
#define WDIM  128
#define NH    125
#define NWO   125

// RY(theta) on qubit Q of 8-dim real state (W-side base state only).
template<int Q>
__device__ __forceinline__ void apply_ry(float (&p)[8], float ang) {
    float s, c;
    __sincosf(0.5f * ang, &s, &c);
    constexpr int lo = 1 << Q;
    #pragma unroll
    for (int i = 0; i < 8; ++i) {
        if ((i & lo) == 0) {
            float a = p[i], b = p[i + lo];
            p[i]      = c * a - s * b;
            p[i + lo] = s * a + c * b;
        }
    }
}

// Block = 192 threads = 3 waves; wave index == input channel.
// Each lane owns a 4-pixel quad (w0..w0+3) of one (b,h) row for ONE channel,
// computes the closed-form class sums, then channels 1,2 push 16 floats
// through LDS (transposed [16][64]: bank = lane%32, 2-way aliasing = free)
// and wave 0 reduces + stores.
__global__ __launch_bounds__(192, 4) void quanv_kernel(
        const float* __restrict__ X,
        const float* __restrict__ Wg,
        float* __restrict__ out) {
    __shared__ float sC[CIN][12];
    __shared__ float sRed[2][16][64];
    const int t = threadIdx.x;
    if (t < CIN) {
        const float* wr = Wg + t * NWGT;
        float p[8];
        #pragma unroll
        for (int m = 0; m < 8; ++m) p[m] = 0.35355339059327373f; // 1/sqrt(8)
        apply_ry<0>(p, wr[0] + wr[3] + wr[6]);
        apply_ry<1>(p, wr[1] + wr[4] + wr[7]);
        apply_ry<2>(p, wr[2] + wr[5] + wr[8]);
        float q1[8], u[8];
        #pragma unroll
        for (int j = 0; j < 8; ++j) q1[j] = p[j ^ ((j & 1) << 1)];        // CX(0,1)
        #pragma unroll
        for (int j = 0; j < 8; ++j) u[j] = q1[j ^ (((j >> 1) & 1) << 2)]; // CX(1,2)

        const float P04 = u[0]*u[0] + u[4]*u[4], P15 = u[1]*u[1] + u[5]*u[5];
        const float P26 = u[2]*u[2] + u[6]*u[6], P37 = u[3]*u[3] + u[7]*u[7];
        const float K1 = 0.5f*(P04 + P15), K2 = 0.5f*(P04 - P15);
        const float K3 = -(u[0]*u[1] + u[4]*u[5]);
        const float L1 = 0.5f*(P26 + P37), L2 = 0.5f*(P26 - P37);
        const float L3 = -(u[2]*u[3] + u[6]*u[7]);
        const float C02 = u[0]*u[2] + u[4]*u[6], C13 = u[1]*u[3] + u[5]*u[7];
        const float M1 = 0.5f*(C02 + C13), M2 = 0.5f*(C02 - C13);
        const float M3 = -0.5f*(u[0]*u[3] + u[1]*u[2] + u[4]*u[7] + u[5]*u[6]);
        sC[t][0] = 0.5f*(K1 + L1); sC[t][1] = 0.5f*(K2 + L2); sC[t][2] = 0.5f*(K3 + L3);
        sC[t][3] = 0.5f*(K1 - L1); sC[t][4] = 0.5f*(K2 - L2); sC[t][5] = 0.5f*(K3 - L3);
        sC[t][6] = M1;             sC[t][7] = M2;             sC[t][8] = M3;
        sC[t][9]  = K1 + L1;       // 2*E1
        sC[t][10] = K1 - L1;       // 2*F1
        sC[t][11] = 2.0f * M1;     // 2*M1
    }
    __syncthreads();

    const int c  = t >> 6;                     // wave index = channel
    const int q  = t & 63;
    const int Qg = blockIdx.x * 64 + q;        // global quad id
    const int w0 = (Qg & 31) << 2;             // 0,4,...,124
    const int row = Qg >> 5;
    const int h  = row & (HDIM - 1);
    const int b  = row >> 7;

    float acc[16];                             // [k*4+j]
    #pragma unroll
    for (int i = 0; i < 16; ++i) acc[i] = 0.f;

    if (h < NH) {
        const bool wfull = (w0 < 124);
        const float* base = X + (((size_t)b * CIN + c) << 14) + (h << 7) + w0;
        const float4 r0 = *(const float4*)(base);
        const float4 r1 = *(const float4*)(base + WDIM);
        const float4 r2 = *(const float4*)(base + 2 * WDIM);
        const float e0 = wfull ? base[4]            : 0.f;
        const float e1 = wfull ? base[WDIM + 4]     : 0.f;
        const float e2 = wfull ? base[2 * WDIM + 4] : 0.f;
        float cs[5];
        cs[0] = r0.x + r1.x + r2.x;
        cs[1] = r0.y + r1.y + r2.y;
        cs[2] = r0.z + r1.z + r2.z;
        cs[3] = r0.w + r1.w + r2.w;
        cs[4] = e0 + e1 + e2;
        float cc[5], sn[5];
        #pragma unroll
        for (int j = 0; j < 5; ++j) __sincosf(cs[j], &sn[j], &cc[j]);

        const float E1 = sC[c][0], E2 = sC[c][1], E3 = sC[c][2];
        const float F1 = sC[c][3], F2 = sC[c][4], F3 = sC[c][5];
        const float M1 = sC[c][6], M2 = sC[c][7], M3 = sC[c][8];
        const float E1x2 = sC[c][9], F1x2 = sC[c][10], M1x2 = sC[c][11];
        #pragma unroll
        for (int j = 0; j < 4; ++j) {
            const float cj = cc[j], sj = sn[j];
            const float c1 = cc[j + 1], s1 = sn[j + 1];
            const float e  = fmaf(E3, sj, fmaf(E2, cj, E1));
            const float f  = fmaf(F3, sj, fmaf(F2, cj, F1));
            const float g  = fmaf(M3, sj, fmaf(M2, cj, M1));
            const float ep = E1x2 - e, fp = F1x2 - f, gp = M1x2 - g;
            const float cls0 = fmaf(-g,  s1, fmaf(f,  c1, e));
            const float cls2 = fmaf(2.f, e,  -cls0);
            const float cls3 = fmaf(-gp, s1, fmaf(fp, c1, ep));
            const float cls1 = fmaf(2.f, ep, -cls3);
            acc[0*4 + j] = cls0; acc[1*4 + j] = cls1;
            acc[2*4 + j] = cls2; acc[3*4 + j] = cls3;
        }
        #pragma unroll
        for (int j = 0; j < 4; ++j)
            if (w0 + j >= NWO) {
                acc[0*4+j] = acc[1*4+j] = acc[2*4+j] = acc[3*4+j] = 0.f;
            }
    }

    // channels 1,2 -> LDS (transposed: addr stride 64 floats => bank = q%32)
    if (c > 0) {
        #pragma unroll
        for (int i = 0; i < 16; ++i) sRed[c - 1][i][q] = acc[i];
    }
    __syncthreads();
    if (c == 0) {
        #pragma unroll
        for (int i = 0; i < 16; ++i) acc[i] += sRed[0][i][q] + sRed[1][i][q];
        float* ob = out + (((size_t)b * 4) << 14) + (h << 7) + w0;
        #pragma unroll
        for (int k = 0; k < 4; ++k)
            *(float4*)(ob + ((size_t)k << 14)) =
                make_float4(acc[k*4+0], acc[k*4+1], acc[k*4+2], acc[k*4+3]);
    }
}

extern "C" void kernel_launch(void* const* d_in, const int* in_sizes, int n_in,
                              void* d_out, int out_size, void* d_ws, size_t ws_size,
                              hipStream_t stream) {
    const float* X  = (const float*)d_in[0];   // (32, 3, 128, 128) f32
    const float* Wg = (const float*)d_in[1];   // (3, 9) f32
    float* out = (float*)d_out;                // (32, 4, 128, 128) f32

    const int nquads = BATCH * HDIM * (WDIM / 4);   // 131072
    const int blocks = nquads / 64;                 // 2048 blocks x 192 thr
    quanv_kernel<<<blocks, 192, 0, stream>>>(X, Wg, out);
}